// Round 10
// baseline (177.966 us; speedup 1.0000x reference)
//
#include <hip/hip_runtime.h>

#define NG 76
#define NPOS (NG * NG)            // 5776
#define NC 85                     // 5 + 80
#define NA 3
#define SPOS 16                   // positions per strip
#define SPP (NPOS / SPOS)         // 361 strips per plane (exact)
#define WPB 4                     // waves per block (256 threads)
#define NWAVES 2048               // persistent waves (8 per CU)
#define STRIDE_F 8.0f             // 608 / 76

typedef float f4 __attribute__((ext_vector_type(4)));

// exp(w) * scaled_anchor * stride == exp(w) * ANCHOR  (scaled = ANCHOR/stride)
__constant__ float c_aw[NA] = {10.0f, 16.0f, 33.0f};
__constant__ float c_ah[NA] = {13.0f, 30.0f, 23.0f};

__device__ __forceinline__ float sigm(float x) {
    return __builtin_amdgcn_rcpf(1.0f + __expf(-x));
}

#define PIN6(r) asm volatile("" : "+v"(r[0]), "+v"(r[1]), "+v"(r[2]), \
                                  "+v"(r[3]), "+v"(r[4]), "+v"(r[5]))

constexpr int NV = NC * 4;        // 340 f4 vectors per strip

// ---- issue the 6 strip loads back-to-back (R9-proven body) ----
__device__ __forceinline__ void strip_load(const float* __restrict__ in,
                                           int s, int l, f4 (&r)[6]) {
    const int plane = (int)((unsigned)s / (unsigned)SPP);
    const int pos0  = (s - plane * SPP) * SPOS;
    const float* ip = in + (size_t)plane * (NC * NPOS) + pos0;
    #pragma unroll
    for (int i = 0; i < 6; ++i) {
        int v = l + i * 64;
        v = v < NV ? v : NV - 1;                      // clamp: dups benign
        r[i] = *reinterpret_cast<const f4*>(ip + (v >> 2) * NPOS + (v & 3) * 4);
    }
}

// ---- transform -> wave-private LDS -> linear store (R9-proven body) ----
__device__ __forceinline__ void strip_process(float* __restrict__ out,
                                              float* L, int s, int l,
                                              const f4 (&r)[6]) {
    const int plane = (int)((unsigned)s / (unsigned)SPP);
    const int strip = s - plane * SPP;
    const int a     = plane - (plane / NA) * NA;
    const int pos0  = strip * SPOS;
    const float aw = c_aw[a];
    const float ah = c_ah[a];
    float* op = out + (size_t)plane * (NPOS * NC) + (size_t)pos0 * NC;

    // iter 0: channels 0..15 (only divergent iteration)
    {
        const int c  = l >> 2;
        const int pq = l & 3;
        const f4 f = r[0];
        f4 o;
        if (c >= 4) {
            o.x = sigm(f.x); o.y = sigm(f.y); o.z = sigm(f.z); o.w = sigm(f.w);
        } else if (c == 2) {
            o.x = __expf(f.x) * aw; o.y = __expf(f.y) * aw;
            o.z = __expf(f.z) * aw; o.w = __expf(f.w) * aw;
        } else if (c == 3) {
            o.x = __expf(f.x) * ah; o.y = __expf(f.y) * ah;
            o.z = __expf(f.z) * ah; o.w = __expf(f.w) * ah;
        } else {
            // 4-aligned position group never crosses a grid row (76%4==0)
            const int pbase = pos0 + pq * 4;
            const int gy  = (int)((unsigned)pbase / (unsigned)NG);
            const int gx0 = pbase - gy * NG;
            if (c == 0) {
                const float g0 = (float)gx0;
                o.x = (sigm(f.x) + g0)        * STRIDE_F;
                o.y = (sigm(f.y) + g0 + 1.0f) * STRIDE_F;
                o.z = (sigm(f.z) + g0 + 2.0f) * STRIDE_F;
                o.w = (sigm(f.w) + g0 + 3.0f) * STRIDE_F;
            } else {
                const float gyf = (float)gy;
                o.x = (sigm(f.x) + gyf) * STRIDE_F;
                o.y = (sigm(f.y) + gyf) * STRIDE_F;
                o.z = (sigm(f.z) + gyf) * STRIDE_F;
                o.w = (sigm(f.w) + gyf) * STRIDE_F;
            }
        }
        const int pb = pq * 4;
        L[(pb + 0) * NC + c] = o.x;                   // <=3-way alias: free
        L[(pb + 1) * NC + c] = o.y;
        L[(pb + 2) * NC + c] = o.z;
        L[(pb + 3) * NC + c] = o.w;
    }
    // iters 1..5: c >= 16 -> pure sigmoid
    #pragma unroll
    for (int i = 1; i < 6; ++i) {
        int v = l + i * 64;
        v = v < NV ? v : NV - 1;
        const int c  = v >> 2;
        const int pb = (v & 3) * 4;
        const f4 f = r[i];
        L[(pb + 0) * NC + c] = sigm(f.x);
        L[(pb + 1) * NC + c] = sigm(f.y);
        L[(pb + 2) * NC + c] = sigm(f.z);
        L[(pb + 3) * NC + c] = sigm(f.w);
    }
    // wave-synchronous LDS handoff: DS pipe is in-order per wave (R6/R7)
    asm volatile("s_waitcnt lgkmcnt(0)" ::: "memory");
    // linear store phase: pure LDS->global copy
    #pragma unroll
    for (int i = 0; i < 6; ++i) {
        int v = l + i * 64;
        v = v < NV ? v : NV - 1;                      // dup store benign
        const f4 o = *reinterpret_cast<const f4*>(&L[v * 4]);
        *reinterpret_cast<f4*>(op + v * 4) = o;
    }
}

// Persistent waves: wave w owns ~8.5 CONSECUTIVE strips, so its 85 read
// pointers + 1 write pointer advance linearly (copy-shaped streams), with a
// 2-deep cross-strip register pipeline (rA/rB, pinned) hiding load latency.
__global__ __launch_bounds__(256) void det_kernel(const float* __restrict__ in,
                                                  float* __restrict__ out,
                                                  int total_strips) {
    __shared__ __align__(16) float lds[WPB][SPOS * NC];   // 4 x 5440 B

    const int t = threadIdx.x, w = t >> 6, l = t & 63;
    const int gw   = blockIdx.x * WPB + w;                // 0..NWAVES-1
    const int sbeg = (int)((long long)gw * total_strips / NWAVES);
    const int send = (int)((long long)(gw + 1) * total_strips / NWAVES);
    if (sbeg >= send) return;
    float* L = lds[w];

    f4 rA[6], rB[6];
    strip_load(in, sbeg, l, rA); PIN6(rA);
    for (int s = sbeg; s < send; s += 2) {
        const bool has1 = (s + 1 < send);
        if (has1) { strip_load(in, s + 1, l, rB); PIN6(rB); }
        strip_process(out, L, s, l, rA);
        if (!has1) break;
        if (s + 2 < send) { strip_load(in, s + 2, l, rA); PIN6(rA); }
        strip_process(out, L, s + 1, l, rB);
    }
}

extern "C" void kernel_launch(void* const* d_in, const int* in_sizes, int n_in,
                              void* d_out, int out_size, void* d_ws, size_t ws_size,
                              hipStream_t stream) {
    const float* x = (const float*)d_in[0];
    float* out     = (float*)d_out;
    const int nB   = in_sizes[0] / (NA * NC * NPOS);      // 16
    const int total_strips = nB * NA * SPP;               // 17328
    det_kernel<<<NWAVES / WPB, 256, 0, stream>>>(x, out, total_strips);
}

// Round 11
// 169.900 us; speedup vs baseline: 1.0475x; 1.0475x over previous
//
#include <hip/hip_runtime.h>

#define NG 76
#define NPOS (NG * NG)            // 5776
#define NC 85                     // 5 + 80
#define NA 3
#define SPOS 16                   // positions per strip
#define SPP (NPOS / SPOS)         // 361 strips per plane (exact)
#define WPB 4                     // waves per block (256 threads)
#define STRIDE_F 8.0f             // 608 / 76

typedef float f4 __attribute__((ext_vector_type(4)));

// exp(w) * scaled_anchor * stride == exp(w) * ANCHOR  (scaled = ANCHOR/stride)
__constant__ float c_aw[NA] = {10.0f, 16.0f, 33.0f};
__constant__ float c_ah[NA] = {13.0f, 30.0f, 23.0f};

__device__ __forceinline__ float sigm(float x) {
    return __builtin_amdgcn_rcpf(1.0f + __expf(-x));
}

#define PIN6(r) asm volatile("" : "+v"(r[0]), "+v"(r[1]), "+v"(r[2]), \
                                  "+v"(r[3]), "+v"(r[4]), "+v"(r[5]))

constexpr int NV = NC * 4;        // 340 f4 vectors per strip

// ---- issue the 6 strip loads back-to-back (R9-proven body) ----
__device__ __forceinline__ void strip_load(const float* __restrict__ in,
                                           int s, int l, f4 (&r)[6]) {
    const int plane = (int)((unsigned)s / (unsigned)SPP);
    const int pos0  = (s - plane * SPP) * SPOS;
    const float* ip = in + (size_t)plane * (NC * NPOS) + pos0;
    #pragma unroll
    for (int i = 0; i < 6; ++i) {
        int v = l + i * 64;
        v = v < NV ? v : NV - 1;                      // clamp: dups benign
        r[i] = *reinterpret_cast<const f4*>(ip + (v >> 2) * NPOS + (v & 3) * 4);
    }
}

// ---- transform -> wave-private LDS -> linear store (R9-proven body) ----
__device__ __forceinline__ void strip_process(float* __restrict__ out,
                                              float* L, int s, int l,
                                              const f4 (&r)[6]) {
    const int plane = (int)((unsigned)s / (unsigned)SPP);
    const int strip = s - plane * SPP;
    const int a     = plane - (plane / NA) * NA;
    const int pos0  = strip * SPOS;
    const float aw = c_aw[a];
    const float ah = c_ah[a];
    float* op = out + (size_t)plane * (NPOS * NC) + (size_t)pos0 * NC;

    // iter 0: channels 0..15 (only divergent iteration)
    {
        const int c  = l >> 2;
        const int pq = l & 3;
        const f4 f = r[0];
        f4 o;
        if (c >= 4) {
            o.x = sigm(f.x); o.y = sigm(f.y); o.z = sigm(f.z); o.w = sigm(f.w);
        } else if (c == 2) {
            o.x = __expf(f.x) * aw; o.y = __expf(f.y) * aw;
            o.z = __expf(f.z) * aw; o.w = __expf(f.w) * aw;
        } else if (c == 3) {
            o.x = __expf(f.x) * ah; o.y = __expf(f.y) * ah;
            o.z = __expf(f.z) * ah; o.w = __expf(f.w) * ah;
        } else {
            // 4-aligned position group never crosses a grid row (76%4==0)
            const int pbase = pos0 + pq * 4;
            const int gy  = (int)((unsigned)pbase / (unsigned)NG);
            const int gx0 = pbase - gy * NG;
            if (c == 0) {
                const float g0 = (float)gx0;
                o.x = (sigm(f.x) + g0)        * STRIDE_F;
                o.y = (sigm(f.y) + g0 + 1.0f) * STRIDE_F;
                o.z = (sigm(f.z) + g0 + 2.0f) * STRIDE_F;
                o.w = (sigm(f.w) + g0 + 3.0f) * STRIDE_F;
            } else {
                const float gyf = (float)gy;
                o.x = (sigm(f.x) + gyf) * STRIDE_F;
                o.y = (sigm(f.y) + gyf) * STRIDE_F;
                o.z = (sigm(f.z) + gyf) * STRIDE_F;
                o.w = (sigm(f.w) + gyf) * STRIDE_F;
            }
        }
        const int pb = pq * 4;
        L[(pb + 0) * NC + c] = o.x;                   // <=3-way alias: free
        L[(pb + 1) * NC + c] = o.y;
        L[(pb + 2) * NC + c] = o.z;
        L[(pb + 3) * NC + c] = o.w;
    }
    // iters 1..5: c >= 16 -> pure sigmoid
    #pragma unroll
    for (int i = 1; i < 6; ++i) {
        int v = l + i * 64;
        v = v < NV ? v : NV - 1;
        const int c  = v >> 2;
        const int pb = (v & 3) * 4;
        const f4 f = r[i];
        L[(pb + 0) * NC + c] = sigm(f.x);
        L[(pb + 1) * NC + c] = sigm(f.y);
        L[(pb + 2) * NC + c] = sigm(f.z);
        L[(pb + 3) * NC + c] = sigm(f.w);
    }
    // wave-synchronous LDS handoff: DS pipe is in-order per wave (R6/R7)
    asm volatile("s_waitcnt lgkmcnt(0)" ::: "memory");
    // linear store phase: pure LDS->global copy
    #pragma unroll
    for (int i = 0; i < 6; ++i) {
        int v = l + i * 64;
        v = v < NV ? v : NV - 1;                      // dup store benign
        const f4 o = *reinterpret_cast<const f4*>(&L[v * 4]);
        *reinterpret_cast<f4*>(op + v * 4) = o;
    }
}

// S-scaling probe: each wave owns 2 consecutive strips, both load sets in
// flight up front (2-deep, pinned), at FULL occupancy (7 blocks/CU via
// 21.76KB LDS, VGPR~64 -> 28 waves/CU). S = 28x2 = 56 strips in flight/CU
// vs 17 (R7) / 16 (R10) -> discriminates latency-scaling vs saturated-server.
__global__ __launch_bounds__(256) void det_kernel(const float* __restrict__ in,
                                                  float* __restrict__ out,
                                                  int total_strips) {
    __shared__ __align__(16) float lds[WPB][SPOS * NC];   // 4 x 5440 B

    const int t = threadIdx.x, w = t >> 6, l = t & 63;
    const int gw = blockIdx.x * WPB + w;                  // wave-job id
    const int s0 = gw * 2;
    if (s0 >= total_strips) return;
    const bool has1 = (s0 + 1 < total_strips);
    float* L = lds[w];

    f4 rA[6], rB[6];
    strip_load(in, s0, l, rA); PIN6(rA);
    if (has1) { strip_load(in, s0 + 1, l, rB); PIN6(rB); }
    strip_process(out, L, s0, l, rA);
    if (has1) strip_process(out, L, s0 + 1, l, rB);
}

extern "C" void kernel_launch(void* const* d_in, const int* in_sizes, int n_in,
                              void* d_out, int out_size, void* d_ws, size_t ws_size,
                              hipStream_t stream) {
    const float* x = (const float*)d_in[0];
    float* out     = (float*)d_out;
    const int nB   = in_sizes[0] / (NA * NC * NPOS);      // 16
    const int total_strips = nB * NA * SPP;               // 17328
    const int jobs   = (total_strips + 1) / 2;            // 8664
    const int blocks = (jobs + WPB - 1) / WPB;            // 2166
    det_kernel<<<blocks, 256, 0, stream>>>(x, out, total_strips);
}